// Round 5
// baseline (289.623 us; speedup 1.0000x reference)
//
#include <hip/hip_runtime.h>

// MS-SSIM, 5 levels, 16x3x512x512 fp32, scalar fp32 out.
//
// R10: TWO launches (conv -> finalize). Nothing is materialized — every
// level recomputes its pixels from img1/img2 (L3-resident, ~100 MB):
//   L0: hpass_direct (R5/R9-proven path, X1 store deleted)
//   L1: hpass_pool1 from img (pool1(img) == X1 bitwise; proven geometry)
//   L2: stage X1-region 52x88 in LDS (stage_pool1, SD=512) + hpass_lds<16>
//   L3: stage X2-region via pool2-from-img + hpass_lds<16>
//   L4: stage X3-region via pool3-from-img + hpass_lds<16>
// All pooling uses 0.25f*((a+b)+(c+d)) at every 2x2 step == reference
// repeated avg_pool2, bitwise. 9696 independent blocks, deep levels first
// (their L3-read-heavy staging overlaps the L0 bulk). Writes = per-block
// partial slots only (written unconditionally -> re-poison safe).
// Block map: [0,96) L4 | [96,480) L3 | [480,2016) L2 | [2016,3552) L1 |
//            [3552,9696) L0.

#define NTHR 512

typedef float v4  __attribute__((ext_vector_type(4)));
typedef float v2f __attribute__((ext_vector_type(2)));

__device__ __forceinline__ float frcp(float x) { return __builtin_amdgcn_rcpf(x); }

#define GW_DEF const float GW[11] = {0.00102840f, 0.00759877f, 0.03600070f, \
    0.10936069f, 0.21300636f, 0.26601172f, 0.21300636f, 0.10936069f,        \
    0.03600070f, 0.00759877f, 0.00102840f};

__device__ __forceinline__ void conv11(const float* s, const float* d,
                                       v4& hs, v4& hd, v4& hss, v4& hdd)
{
    GW_DEF
    #pragma unroll
    for (int j = 0; j < 11; ++j) {
        float w = GW[j];
        v4 sv = {s[j], s[j+1], s[j+2], s[j+3]};
        v4 dv = {d[j], d[j+1], d[j+2], d[j+3]};
        v4 wsv = w * sv, wdv = w * dv;
        hs += wsv; hd += wdv; hss += wsv * sv; hdd += wdv * dv;
    }
}

// ---- h-pass: direct source rows (level pixels in global)
template<int TROWS>
__device__ void hpass_direct(const float* __restrict__ p1, const float* __restrict__ p2,
                             int H, int tx0, int ty0, v4* hb)
{
    constexpr int HR = TROWS + 10;
    for (int task = threadIdx.x; task < HR * 8; task += NTHR) {
        const int r = task >> 3, cg2 = task & 7;
        const int gr = ty0 + r;
        const int c0 = tx0 + cg2 * 4;
        v4 hs = 0.f, hd = 0.f, hss = 0.f, hdd = 0.f;
        if (gr < H) {
            float s[16], d[16];
            if (c0 + 16 <= H) {
                const float* pa = p1 + (size_t)gr * H + c0;
                const float* pb = p2 + (size_t)gr * H + c0;
                #pragma unroll
                for (int q = 0; q < 4; ++q) {
                    v4 va = *(const v4*)(pa + 4 * q);
                    v4 vb = *(const v4*)(pb + 4 * q);
                    v4 sv = va + vb, dv = va - vb;
                    s[4*q+0] = sv.x; s[4*q+1] = sv.y; s[4*q+2] = sv.z; s[4*q+3] = sv.w;
                    d[4*q+0] = dv.x; d[4*q+1] = dv.y; d[4*q+2] = dv.z; d[4*q+3] = dv.w;
                }
            } else {
                #pragma unroll
                for (int q = 0; q < 16; ++q) {
                    int cc = c0 + q;
                    float a = (cc < H) ? p1[(size_t)gr * H + cc] : 0.f;
                    float b = (cc < H) ? p2[(size_t)gr * H + cc] : 0.f;
                    s[q] = a + b; d[q] = a - b;
                }
            }
            conv11(s, d, hs, hd, hss, hdd);
        }
        v4* row = &hb[r * 33 + cg2 * 4];
        row[0] = (v4){hs.x, hd.x, hss.x, hdd.x};
        row[1] = (v4){hs.y, hd.y, hss.y, hdd.y};
        row[2] = (v4){hs.z, hd.z, hss.z, hdd.z};
        row[3] = (v4){hs.w, hd.w, hss.w, hdd.w};
    }
}

// ---- h-pass: level pixels = 2x2 pool of source (global), inline.
// H = level dim; source dim = 2H.
template<int TROWS>
__device__ void hpass_pool1(const float* __restrict__ q1, const float* __restrict__ q2,
                            int H, int tx0, int ty0, v4* hb)
{
    constexpr int HR = TROWS + 10;
    const int HS = 2 * H;
    for (int task = threadIdx.x; task < HR * 8; task += NTHR) {
        const int r = task >> 3, cg2 = task & 7;
        const int gr = ty0 + r;
        const int c0 = tx0 + cg2 * 4;
        v4 hs = 0.f, hd = 0.f, hss = 0.f, hdd = 0.f;
        if (gr < H) {
            float s[16], d[16];
            const int iy = 2 * gr;
            if (c0 + 16 <= H) {
                const float* a0 = q1 + (size_t)iy * HS + 2 * c0;
                const float* b0 = q2 + (size_t)iy * HS + 2 * c0;
                #pragma unroll
                for (int q = 0; q < 8; ++q) {
                    v4 xa0 = *(const v4*)(a0 + 4 * q);
                    v4 xa1 = *(const v4*)(a0 + HS + 4 * q);
                    v4 xb0 = *(const v4*)(b0 + 4 * q);
                    v4 xb1 = *(const v4*)(b0 + HS + 4 * q);
                    float pa0 = 0.25f * ((xa0.x + xa0.y) + (xa1.x + xa1.y));
                    float pa1 = 0.25f * ((xa0.z + xa0.w) + (xa1.z + xa1.w));
                    float pb0 = 0.25f * ((xb0.x + xb0.y) + (xb1.x + xb1.y));
                    float pb1 = 0.25f * ((xb0.z + xb0.w) + (xb1.z + xb1.w));
                    s[2*q]   = pa0 + pb0; d[2*q]   = pa0 - pb0;
                    s[2*q+1] = pa1 + pb1; d[2*q+1] = pa1 - pb1;
                }
            } else {
                #pragma unroll
                for (int q = 0; q < 16; ++q) {
                    int cc = c0 + q;
                    float pa = 0.f, pb = 0.f;
                    if (cc < H) {
                        const float* qa = q1 + (size_t)iy * HS + 2 * cc;
                        const float* qb = q2 + (size_t)iy * HS + 2 * cc;
                        pa = 0.25f * ((qa[0] + qa[1]) + (qa[HS] + qa[HS + 1]));
                        pb = 0.25f * ((qb[0] + qb[1]) + (qb[HS] + qb[HS + 1]));
                    }
                    s[q] = pa + pb; d[q] = pa - pb;
                }
            }
            conv11(s, d, hs, hd, hss, hdd);
        }
        v4* row = &hb[r * 33 + cg2 * 4];
        row[0] = (v4){hs.x, hd.x, hss.x, hdd.x};
        row[1] = (v4){hs.y, hd.y, hss.y, hdd.y};
        row[2] = (v4){hs.z, hd.z, hss.z, hdd.z};
        row[3] = (v4){hs.w, hd.w, hss.w, hdd.w};
    }
}

// ---- h-pass: level pixels = 2x2 pool of LDS region (pitch 89, origin =
// source-level coords (2*ty0, 2*tx0)). H = level dim.
template<int TROWS>
__device__ void hpass_lds(const float* la, const float* lb,
                          int H, int tx0, int ty0, v4* hb)
{
    constexpr int HR = TROWS + 10;
    for (int task = threadIdx.x; task < HR * 8; task += NTHR) {
        const int r = task >> 3, cg2 = task & 7;
        const int gr = ty0 + r;
        const int c0 = tx0 + cg2 * 4;
        v4 hs = 0.f, hd = 0.f, hss = 0.f, hdd = 0.f;
        if (gr < H) {
            float s[16], d[16];
            const int lr = 2 * r;
            #pragma unroll
            for (int q = 0; q < 16; ++q) {
                int cc = c0 + q;
                float pa = 0.f, pb = 0.f;
                if (cc < H) {
                    int lc = 2 * (cc - tx0);
                    const float* a0 = la + lr * 89 + lc;
                    const float* b0 = lb + lr * 89 + lc;
                    pa = 0.25f * ((a0[0] + a0[1]) + (a0[89] + a0[90]));
                    pb = 0.25f * ((b0[0] + b0[1]) + (b0[89] + b0[90]));
                }
                s[q] = pa + pb; d[q] = pa - pb;
            }
            conv11(s, d, hs, hd, hss, hdd);
        }
        v4* row = &hb[r * 33 + cg2 * 4];
        row[0] = (v4){hs.x, hd.x, hss.x, hdd.x};
        row[1] = (v4){hs.y, hd.y, hss.y, hdd.y};
        row[2] = (v4){hs.z, hd.z, hss.z, hdd.z};
        row[3] = (v4){hs.w, hd.w, hss.w, hdd.w};
    }
}

// Stage 52x88 region (pitch 89) of pool1(src). Dest coords bound DB,
// source dim SD = 2*DB. Region origin (2*ty0, 2*tx0) in dest coords.
__device__ void stage_pool1(const float* __restrict__ s1, const float* __restrict__ s2,
                            int SD, int DB, int tx0, int ty0, float* la, float* lb)
{
    for (int t = threadIdx.x; t < 2 * 52 * 44; t += NTHR) {
        int im = t >= 52 * 44; int tt = im ? t - 52 * 44 : t;
        int rr = tt / 44, cp = tt % 44;
        int xr = 2 * ty0 + rr, xc = 2 * tx0 + 2 * cp;
        const float* sp = im ? s2 : s1;
        float* lp = im ? lb : la;
        float v0 = 0.f, v1 = 0.f;
        if (xr < DB && xc < DB) {
            const float* q0 = sp + (size_t)(2 * xr) * SD + 2 * xc;
            v4 r0 = *(const v4*)q0;
            v4 r1 = *(const v4*)(q0 + SD);
            v0 = 0.25f * ((r0.x + r0.y) + (r1.x + r1.y));
            v1 = 0.25f * ((r0.z + r0.w) + (r1.z + r1.w));
        }
        lp[rr * 89 + 2 * cp]     = v0;
        lp[rr * 89 + 2 * cp + 1] = v1;
    }
}

// Stage 52x88 region of pool2(src). Dest bound DB, source dim SD = 4*DB.
__device__ void stage_pool2(const float* __restrict__ s1, const float* __restrict__ s2,
                            int SD, int DB, int tx0, int ty0, float* la, float* lb)
{
    for (int t = threadIdx.x; t < 2 * 52 * 88; t += NTHR) {
        int im = t >= 52 * 88; int tt = im ? t - 52 * 88 : t;
        int rr = tt / 88, cc = tt % 88;
        int yr = 2 * ty0 + rr, yc = 2 * tx0 + cc;
        const float* sp = im ? s2 : s1;
        float* lp = im ? lb : la;
        float v = 0.f;
        if (yr < DB && yc < DB) {
            const float* q = sp + (size_t)(4 * yr) * SD + 4 * yc;
            v4 r0 = *(const v4*)q;
            v4 r1 = *(const v4*)(q + SD);
            v4 r2 = *(const v4*)(q + 2 * SD);
            v4 r3 = *(const v4*)(q + 3 * SD);
            float a00 = 0.25f * ((r0.x + r0.y) + (r1.x + r1.y));
            float a01 = 0.25f * ((r0.z + r0.w) + (r1.z + r1.w));
            float a10 = 0.25f * ((r2.x + r2.y) + (r3.x + r3.y));
            float a11 = 0.25f * ((r2.z + r2.w) + (r3.z + r3.w));
            v = 0.25f * ((a00 + a01) + (a10 + a11));
        }
        lp[rr * 89 + cc] = v;
    }
}

// Stage 52x88 region of pool3(src). Dest bound DB, source dim SD = 8*DB.
__device__ void stage_pool3(const float* __restrict__ s1, const float* __restrict__ s2,
                            int SD, int DB, int tx0, int ty0, float* la, float* lb)
{
    for (int t = threadIdx.x; t < 2 * 52 * 88; t += NTHR) {
        int im = t >= 52 * 88; int tt = im ? t - 52 * 88 : t;
        int rr = tt / 88, cc = tt % 88;
        int yr = 2 * ty0 + rr, yc = 2 * tx0 + cc;
        const float* sp = im ? s2 : s1;
        float* lp = im ? lb : la;
        float v = 0.f;
        if (yr < DB && yc < DB) {
            const float* q = sp + (size_t)(8 * yr) * SD + 8 * yc;
            float p2h[2][2];                  // [vhalf][hhalf] 4x4 pool2 vals
            #pragma unroll
            for (int h = 0; h < 2; ++h) {
                const float* qq = q + (size_t)(4 * h) * SD;
                v4 A0 = *(const v4*)qq;
                v4 A1 = *(const v4*)(qq + SD);
                v4 A2 = *(const v4*)(qq + 2 * SD);
                v4 A3 = *(const v4*)(qq + 3 * SD);
                v4 B0 = *(const v4*)(qq + 4);
                v4 B1 = *(const v4*)(qq + SD + 4);
                v4 B2 = *(const v4*)(qq + 2 * SD + 4);
                v4 B3 = *(const v4*)(qq + 3 * SD + 4);
                float p00 = 0.25f * ((A0.x + A0.y) + (A1.x + A1.y));
                float p01 = 0.25f * ((A0.z + A0.w) + (A1.z + A1.w));
                float p10 = 0.25f * ((A2.x + A2.y) + (A3.x + A3.y));
                float p11 = 0.25f * ((A2.z + A2.w) + (A3.z + A3.w));
                float q00 = 0.25f * ((B0.x + B0.y) + (B1.x + B1.y));
                float q01 = 0.25f * ((B0.z + B0.w) + (B1.z + B1.w));
                float q10 = 0.25f * ((B2.x + B2.y) + (B3.x + B3.y));
                float q11 = 0.25f * ((B2.z + B2.w) + (B3.z + B3.w));
                p2h[h][0] = 0.25f * ((p00 + p01) + (p10 + p11));
                p2h[h][1] = 0.25f * ((q00 + q01) + (q10 + q11));
            }
            v = 0.25f * ((p2h[0][0] + p2h[0][1]) + (p2h[1][0] + p2h[1][1]));
        }
        lp[rr * 89 + cc] = v;
    }
}

// ---- vertical pass + ssim/cs + block reduction (proven, verbatim)
template<int TROWS>
__device__ void vpass_reduce(int H, int tx0, int ty0, const v4* hb, float* red,
                             float* __restrict__ partS, float* __restrict__ partC)
{
    constexpr int OPT = TROWS * 32 / NTHR;
    constexpr int NW  = NTHR / 64;
    GW_DEF
    const float C1 = 1e-4f, C2 = 9e-4f;
    const int tid   = threadIdx.x;
    const int outHW = H - 10;
    const int col   = tid & 31;
    const int row0  = (tid >> 5) * OPT;
    const float colm = (tx0 + col < outHW) ? 1.f : 0.f;
    v4 A[OPT];
    #pragma unroll
    for (int k = 0; k < OPT; ++k) A[k] = 0.f;

    #pragma unroll
    for (int r = 0; r < OPT + 10; ++r) {
        v4 h = hb[(row0 + r) * 33 + col];
        #pragma unroll
        for (int k = 0; k < OPT; ++k) {
            const int j = r - k;
            if (j >= 0 && j < 11) A[k] += GW[j] * h;
        }
    }

    float ssim_t = 0.f, cs_t = 0.f;
    #pragma unroll
    for (int k = 0; k < OPT; ++k) {
        float mask = colm * ((ty0 + row0 + k < outHW) ? 1.f : 0.f);
        float mu_s = A[k].x, mu_d = A[k].y;
        float P = mu_s * mu_s, Q = mu_d * mu_d;
        float U = A[k].z - P, V = A[k].w - Q;
        float v1 = 0.5f * (U - V) + C2;
        float v2 = 0.5f * (U + V) + C2;
        float n1 = 0.5f * (P - Q) + C1;
        float d1 = 0.5f * (P + Q) + C1;
        float csv = v1 * frcp(v2);
        float ssv = n1 * csv * frcp(d1);
        cs_t   += mask * csv;
        ssim_t += mask * ssv;
    }

    #pragma unroll
    for (int off = 32; off > 0; off >>= 1) {
        ssim_t += __shfl_down(ssim_t, off);
        cs_t   += __shfl_down(cs_t, off);
    }
    int wave = tid >> 6, lane = tid & 63;
    if (lane == 0) { red[wave] = ssim_t; red[NW + wave] = cs_t; }
    __syncthreads();
    if (tid == 0) {
        float s = 0.f, c = 0.f;
        #pragma unroll
        for (int w = 0; w < NW; ++w) { s += red[w]; c += red[NW + w]; }
        partS[0] = s; partC[0] = c;
    }
}

// ---- the conv kernel: all 5 levels, 9696 independent blocks
__global__ __launch_bounds__(NTHR, 6) void conv_kernel(
    const float* __restrict__ img1, const float* __restrict__ img2,
    float* __restrict__ accS, float* __restrict__ accC)
{
    __shared__ v4 smemv[3172];          // 50,752 B union
    __shared__ float red[16];
    v4* hb    = smemv;                  // T64: 74*33 v4 = 39,072 B
    float* la = (float*)smemv + 3432;   // T16: hb 26*33 v4 = 3432 fl, then
    float* lb = la + 52 * 89;           // two 52x89 regions

    const int b = (int)blockIdx.x;
    const size_t IMS = (size_t)512 * 512;

    if (b >= 3552) {                    // L0: H=512, T64, 16x8x48
        int lbk = b - 3552;
        int cx = lbk & 15, rem = lbk >> 4, cy = rem & 7, nc = rem >> 3;
        const float* p1 = img1 + (size_t)nc * IMS;
        const float* p2 = img2 + (size_t)nc * IMS;
        int tx0 = cx * 32, ty0 = cy * 64;
        hpass_direct<64>(p1, p2, 512, tx0, ty0, hb);
        __syncthreads();
        vpass_reduce<64>(512, tx0, ty0, hb, red, accS + b, accC + b);
    } else if (b >= 2016) {             // L1: H=256, T64, 8x4x48, pool1(img)
        int lbk = b - 2016;
        int cx = lbk & 7, rem = lbk >> 3, cy = rem & 3, nc = rem >> 2;
        const float* p1 = img1 + (size_t)nc * IMS;
        const float* p2 = img2 + (size_t)nc * IMS;
        int tx0 = cx * 32, ty0 = cy * 64;
        hpass_pool1<64>(p1, p2, 256, tx0, ty0, hb);
        __syncthreads();
        vpass_reduce<64>(256, tx0, ty0, hb, red, accS + b, accC + b);
    } else if (b >= 480) {              // L2: H=128, T16, 4x8x48, staged X1
        int lbk = b - 480;
        int cx = lbk & 3, rem = lbk >> 2, cy = rem & 7, nc = rem >> 3;
        const float* p1 = img1 + (size_t)nc * IMS;
        const float* p2 = img2 + (size_t)nc * IMS;
        int tx0 = cx * 32, ty0 = cy * 16;
        stage_pool1(p1, p2, 512, 256, tx0, ty0, la, lb);
        __syncthreads();
        hpass_lds<16>(la, lb, 128, tx0, ty0, hb);
        __syncthreads();
        vpass_reduce<16>(128, tx0, ty0, hb, red, accS + b, accC + b);
    } else if (b >= 96) {               // L3: H=64, T16, 2x4x48, staged X2
        int lbk = b - 96;
        int cx = lbk & 1, rem = lbk >> 1, cy = rem & 3, nc = rem >> 2;
        const float* p1 = img1 + (size_t)nc * IMS;
        const float* p2 = img2 + (size_t)nc * IMS;
        int tx0 = cx * 32, ty0 = cy * 16;
        stage_pool2(p1, p2, 512, 128, tx0, ty0, la, lb);
        __syncthreads();
        hpass_lds<16>(la, lb, 64, tx0, ty0, hb);
        __syncthreads();
        vpass_reduce<16>(64, tx0, ty0, hb, red, accS + b, accC + b);
    } else {                            // L4: H=32, T16, 1x2x48, staged X3
        int cy = b & 1, nc = b >> 1;
        const float* p1 = img1 + (size_t)nc * IMS;
        const float* p2 = img2 + (size_t)nc * IMS;
        int tx0 = 0, ty0 = cy * 16;
        stage_pool3(p1, p2, 512, 64, tx0, ty0, la, lb);
        __syncthreads();
        hpass_lds<16>(la, lb, 32, tx0, ty0, hb);
        __syncthreads();
        vpass_reduce<16>(32, tx0, ty0, hb, red, accS + b, accC + b);
    }
}

// ---- finalize: sum partial slots, pow weights
__global__ void finalize_kernel(const float* __restrict__ accS, const float* __restrict__ accC,
                                float* __restrict__ out)
{
    __shared__ float sm[10];
    __shared__ float wred[8];
    const int tid  = (int)threadIdx.x;
    const int wave = tid >> 6, lane = tid & 63;
    // level -> slot range
    const int st[5] = {3552, 2016, 480, 96, 0};
    const int en[5] = {9696, 3552, 2016, 480, 96};

    for (int srs = 0; srs < 10; ++srs) {
        int l = srs >> 1;
        const float* base = (srs & 1) ? accC : accS;
        float p = 0.f;
        for (int i = st[l] + tid; i < en[l]; i += NTHR) p += base[i];
        #pragma unroll
        for (int o = 32; o > 0; o >>= 1) p += __shfl_down(p, o);
        if (lane == 0) wred[wave] = p;
        __syncthreads();
        if (tid == 0) {
            float t = 0.f;
            #pragma unroll
            for (int w = 0; w < 8; ++w) t += wred[w];
            sm[srs] = t;
        }
        __syncthreads();
    }

    if (tid == 0) {
        const float w[5] = {0.0448f, 0.2856f, 0.3001f, 0.2363f, 0.1333f};
        float ms[5], mc[5];
        for (int l = 0; l < 5; ++l) {
            int oh = (512 >> l) - 10;
            float cnt = 48.f * (float)oh * (float)oh;
            ms[l] = (sm[2 * l] / cnt + 1.f) * 0.5f;
            mc[l] = (sm[2 * l + 1] / cnt + 1.f) * 0.5f;
        }
        float p2 = powf(ms[4], w[4]);
        float r = 1.f;
        for (int i = 0; i < 4; ++i) r *= powf(mc[i], w[i]) * p2;
        out[0] = r;
    }
}

extern "C" void kernel_launch(void* const* d_in, const int* in_sizes, int n_in,
                              void* d_out, int out_size, void* d_ws, size_t ws_size,
                              hipStream_t stream)
{
    (void)in_sizes; (void)n_in; (void)out_size; (void)ws_size;
    const float* img1 = (const float*)d_in[0];
    const float* img2 = (const float*)d_in[1];
    float* out = (float*)d_out;
    float* ws  = (float*)d_ws;

    // workspace (floats): accS[9696] accC[9696] — nothing else.
    float* accS = ws;
    float* accC = accS + 9696;

    conv_kernel<<<dim3(9696), NTHR, 0, stream>>>(img1, img2, accS, accC);
    finalize_kernel<<<1, NTHR, 0, stream>>>(accS, accC, out);
}